// Round 4
// baseline (615.290 us; speedup 1.0000x reference)
//
#include <hip/hip_runtime.h>

#define DIM 512
#define N_ROWS 16384
#define K_CODES 8192
#define BK 32
#define TM 128
#define TN 128
#define NG (K_CODES / TN)               // 64 code groups
#define OUT_ELEMS (N_ROWS * DIM)        // 8388608
#define MARGIN 0.125f
#define RESCAN_CHUNK 1024
#define RESCAN_NCHUNK (K_CODES / RESCAN_CHUNK)  // 8
#define RESCAN_ROWS 8
#define NT (DIM / BK)                   // 16 K-steps

typedef _Float16 f16;
typedef _Float16 f16x8 __attribute__((ext_vector_type(8)));
typedef float f32x4 __attribute__((ext_vector_type(4)));

// monotone float->uint map: min on packed == (min dist, then min idx)
__device__ __forceinline__ unsigned long long pack_di(float d, int i) {
  unsigned u = __float_as_uint(d);
  u = (u & 0x80000000u) ? ~u : (u | 0x80000000u);
  return ((unsigned long long)u << 32) | (unsigned)i;
}

// ---------------- kernel 0: fp32 -> fp16 cast (x) ----------------
__global__ __launch_bounds__(256) void vq_split_kernel(const float* __restrict__ src,
                                                       f16* __restrict__ x16) {
  int i = (blockIdx.x * 256 + threadIdx.x) * 8;
  float4 v0 = *(const float4*)(src + i);
  float4 v1 = *(const float4*)(src + i + 4);
  float f[8] = {v0.x, v0.y, v0.z, v0.w, v1.x, v1.y, v1.z, v1.w};
  f16x8 h;
  #pragma unroll
  for (int j = 0; j < 8; ++j) h[j] = (f16)f[j];   // RNE, rel err <= 2^-11
  *(f16x8*)(x16 + i) = h;
}

// ---------------- kernel 1: emb fp16 cast + exact fp32 norms + counter zero ----------------
// one wave per code row: 64 lanes x 8 elems = 512
__global__ __launch_bounds__(256) void vq_split_enorm_kernel(
    const float* __restrict__ emb, f16* __restrict__ e16,
    float* __restrict__ enorm, int* __restrict__ counter) {
  int gid  = blockIdx.x * 256 + threadIdx.x;
  if (gid == 0) *counter = 0;
  int code = gid >> 6;
  int lane = gid & 63;
  size_t off = (size_t)code * DIM + lane * 8;
  float4 v0 = *(const float4*)(emb + off);
  float4 v1 = *(const float4*)(emb + off + 4);
  float f[8] = {v0.x, v0.y, v0.z, v0.w, v1.x, v1.y, v1.z, v1.w};
  f16x8 h;
  float s = 0.0f;
  #pragma unroll
  for (int j = 0; j < 8; ++j) {
    h[j] = (f16)f[j];
    s = fmaf(f[j], f[j], s);
  }
  *(f16x8*)(e16 + off) = h;
  #pragma unroll
  for (int o = 32; o > 0; o >>= 1) s += __shfl_down(s, o);
  if (lane == 0) enorm[code] = s;
}

// ---------------- async global->LDS 16B helper ----------------
__device__ __forceinline__ void gl2lds16(const f16* g, f16* l) {
  __builtin_amdgcn_global_load_lds((const __attribute__((address_space(1))) unsigned int*)g,
                                   (__attribute__((address_space(3))) unsigned int*)l,
                                   16, 0, 0);
}

__device__ __forceinline__ void top2_merge(float& d1, int& i1, float& d2,
                                           float od1, int oi1, float od2) {
  if (od1 < d1 || (od1 == d1 && oi1 < i1)) {
    d2 = fminf(d1, od2);
    d1 = od1; i1 = oi1;
  } else {
    d2 = fminf(d2, od1);
  }
}

// ---------------- kernel 2: single-term fp16 MFMA GEMM + top-2 argmin ----------------
// sim = x16.e16 (fp16 in, exact fp32 accumulate); dist = ||e||^2 - 2 sim.
// Rows with top-2 gap < MARGIN get the exact fp32 rescan, so argmin is exact.
//
// Round-4 structure: LDS-bandwidth diet. Round-3 audit: 48 KB/block/K-step
// through the 85 B/cyc LDS pipe (~36k cyc/CU/batch) vs MFMA's 20k -> LDS was
// the binding pipe, matching MfmaUtil 26%. Fix: A-fragments load DIRECTLY
// global->VGPR (identical per-lane addresses and coalescing shape as the old
// gl2lds staging; wave pairs reading the same rows dedup in L1/L2), register
// double-buffered (aC/aN). Only B goes through LDS (real 2x cross-wave reuse),
// keeping the round-3-proven stage-ahead double-buffer + XOR swizzle:
// LDS/block/step drops 48 KB -> 24 KB, below the MFMA budget.
//
// B LDS tile [128][BK=32] f16, chunk fq of row r at slot fq ^ ((r>>1)&3);
// gl2lds writes linearly so the swizzle is realized source-side (lane l
// fetches chunk (l&3)^((l>>3)&3) of row l>>2). Conflict-free (rounds 0-3).
__global__ __launch_bounds__(256, 4) void vq_argmin_mfma_kernel(
    const f16* __restrict__ x16, const f16* __restrict__ e16,
    const float* __restrict__ enorm,
    float* __restrict__ cand_d1, int* __restrict__ cand_i1, float* __restrict__ cand_d2) {
  __shared__ __align__(16) f16 Be[2][TN * BK];   // 8 KB per buffer
  __shared__ float red_d1[2][TM];
  __shared__ int   red_i1[2][TM];
  __shared__ float red_d2[2][TM];

  const int tid  = threadIdx.x;
  const int wave = tid >> 6;
  const int lane = tid & 63;
  const int bm = blockIdx.x, bn = blockIdx.y;
  const int wr = (wave >> 1) * 64;   // wave's row offset in tile
  const int wc = (wave & 1) * 64;    // wave's col offset in tile

  // B staging: wave w stages rows [w*32, w*32+32) via 2 issues of 16 rows.
  // source-side swizzle: lane l fetches chunk (l&3)^((l>>3)&3) of row l>>2.
  const f16* gB;
  {
    const int srow = lane >> 2;                              // 0..15
    const int scg  = ((lane & 3) ^ ((lane >> 3) & 3)) * 8;   // swizzled chunk * 8 elems
    gB = e16 + (size_t)(bn * TN + wave * 32 + srow) * DIM + scg;
  }
  f16* dstB0 = &Be[0][wave * 32 * BK];
  f16* dstB1 = &Be[1][wave * 32 * BK];

  const int fr = lane & 15;   // fragment row/col within 16
  const int fq = lane >> 4;   // k-quad
  const int sw8 = (fq ^ ((fr >> 1) & 3)) * 8;   // read-side swizzled chunk * 8 elems

  // A direct-to-register: 32-bit element indices (SGPR base + voffset form).
  unsigned aidx[4];
  #pragma unroll
  for (int f = 0; f < 4; ++f)
    aidx[f] = (unsigned)(bm * TM + wr + f * 16 + fr) * DIM + fq * 8;

  f32x4 acc[4][4];
  #pragma unroll
  for (int i = 0; i < 4; ++i)
    #pragma unroll
    for (int j = 0; j < 4; ++j)
      acc[i][j] = (f32x4){0.f, 0.f, 0.f, 0.f};

  // prologue: stage B step 0 into buffer 0; load A frags step 0 into regs
  gl2lds16(gB,            dstB0);
  gl2lds16(gB + 16 * DIM, dstB0 + 16 * BK);
  f16x8 aC[4], aN[4];
  #pragma unroll
  for (int f = 0; f < 4; ++f) aC[f] = *(const f16x8*)(x16 + aidx[f]);
  __syncthreads();   // vmcnt(0): B tile 0 resident (a-loads also drained; used now)

  #pragma unroll 2
  for (int s = 0; s < NT; ++s) {
    const int cur = s & 1;
    // stage-ahead: next B tile into the other buffer + next A frags into regs,
    // all issued BEFORE this step's compute so the end-of-step barrier's
    // vmcnt(0) drain is covered by 16 MFMAs + 4 ds_reads.
    if (s + 1 < NT) {
      f16* nb = cur ? dstB0 : dstB1;
      gl2lds16(gB + (s + 1) * BK,            nb);
      gl2lds16(gB + (s + 1) * BK + 16 * DIM, nb + 16 * BK);
      #pragma unroll
      for (int f = 0; f < 4; ++f)
        aN[f] = *(const f16x8*)(x16 + aidx[f] + (s + 1) * BK);
    }

    const f16* B = cur ? &Be[1][0] : &Be[0][0];
    f16x8 b[4];
    #pragma unroll
    for (int f = 0; f < 4; ++f)
      b[f] = *(const f16x8*)&B[(wc + f * 16 + fr) * BK + sw8];
    #pragma unroll
    for (int mf = 0; mf < 4; ++mf)
      #pragma unroll
      for (int nf = 0; nf < 4; ++nf)
        acc[mf][nf] = __builtin_amdgcn_mfma_f32_16x16x32_f16(aC[mf], b[nf], acc[mf][nf], 0, 0, 0);

    #pragma unroll
    for (int f = 0; f < 4; ++f) aC[f] = aN[f];   // reg dbuf swap (renamed by unroll-2)
    __syncthreads();   // drains stage-ahead loads (covered by compute) + joins waves
  }

  // ---- epilogue: distances + per-row top-2 over this block's 128 cols ----
  float en[4];
  #pragma unroll
  for (int nf = 0; nf < 4; ++nf)
    en[nf] = enorm[bn * TN + wc + nf * 16 + fr];

  #pragma unroll
  for (int mf = 0; mf < 4; ++mf) {
    #pragma unroll
    for (int reg = 0; reg < 4; ++reg) {
      float d1 = 3.4e38f, d2 = 3.4e38f;
      int i1 = 0;
      #pragma unroll
      for (int nf = 0; nf < 4; ++nf) {   // ascending col keeps lowest idx on ties
        float d = en[nf] - 2.0f * acc[mf][nf][reg];
        int ci = bn * TN + wc + nf * 16 + fr;
        if (d < d1) { d2 = d1; d1 = d; i1 = ci; }
        else if (d < d2) { d2 = d; }
      }
      // butterfly over the 16 lanes (same fq) holding this row's 64 cols
      #pragma unroll
      for (int m = 1; m <= 8; m <<= 1) {
        float od1 = __shfl_xor(d1, m, 16);
        int   oi1 = __shfl_xor(i1, m, 16);
        float od2 = __shfl_xor(d2, m, 16);
        top2_merge(d1, i1, d2, od1, oi1, od2);
      }
      if (fr == 0) {
        int row = wr + mf * 16 + fq * 4 + reg;
        red_d1[wave & 1][row] = d1;
        red_i1[wave & 1][row] = i1;
        red_d2[wave & 1][row] = d2;
      }
    }
  }
  __syncthreads();
  if (tid < TM) {
    float d1 = red_d1[0][tid]; int i1 = red_i1[0][tid]; float d2 = red_d2[0][tid];
    top2_merge(d1, i1, d2, red_d1[1][tid], red_i1[1][tid], red_d2[1][tid]);
    size_t o = (size_t)bn * N_ROWS + (size_t)bm * TM + tid;
    cand_d1[o] = d1; cand_i1[o] = i1; cand_d2[o] = d2;
  }
}

// ---------------- kernel 3: merge 64 groups -> idx, flag + compacted work list ----------------
__global__ __launch_bounds__(256) void vq_merge2_kernel(
    const float* __restrict__ cd1, const int* __restrict__ ci1, const float* __restrict__ cd2,
    int* __restrict__ idx, int* __restrict__ flag,
    int* __restrict__ counter, int* __restrict__ flagged,
    unsigned long long* __restrict__ packed,
    float* __restrict__ loss_slot) {
  int r = blockIdx.x * 256 + threadIdx.x;
  if (r == 0) *loss_slot = 0.0f;
  float d1 = 3.4e38f, d2 = 3.4e38f;
  int i1 = 0;
  for (int g = 0; g < NG; ++g) {   // ascending g = ascending col blocks
    size_t o = (size_t)g * N_ROWS + r;
    top2_merge(d1, i1, d2, cd1[o], ci1[o], cd2[o]);
  }
  idx[r] = i1;
  int f = (d2 - d1 < MARGIN) ? 1 : 0;
  flag[r] = f;
  if (f) {
    packed[r] = 0xFFFFFFFFFFFFFFFFULL;
    int slot = atomicAdd(counter, 1);
    flagged[slot] = r;
  }
}

// ---------------- kernel 4: exact fp32 rescan, 8 rows per codebook pass ----------------
// Per-code arithmetic (s0..s3 lanes, (s0+s1)+(s2+s3)) kept bit-identical to the
// verified round-0 rescan; only the batching over rows changed.
__global__ __launch_bounds__(256) void vq_rescan_kernel(
    const float* __restrict__ x, const float* __restrict__ emb,
    const float* __restrict__ enorm,
    const int* __restrict__ counter, const int* __restrict__ flagged,
    unsigned long long* __restrict__ packed) {
  __shared__ float4 xs[RESCAN_ROWS][DIM / 4];          // 16 KB
  __shared__ unsigned long long wmin[4][RESCAN_ROWS];  // 256 B
  const int t  = threadIdx.x;
  const int wv = t >> 6, ln = t & 63;
  const int nflag   = counter[0];
  const int ngroups = (nflag + RESCAN_ROWS - 1) / RESCAN_ROWS;
  const int nitems  = ngroups * RESCAN_NCHUNK;
  for (int item = blockIdx.x; item < nitems; item += gridDim.x) {
    const int g  = item / RESCAN_NCHUNK;
    const int c0 = (item % RESCAN_NCHUNK) * RESCAN_CHUNK;
    __syncthreads();   // protect xs from previous iteration's readers
    #pragma unroll
    for (int u = 0; u < 4; ++u) {
      int i4 = u * 256 + t;                 // 0..1023 float4 slots
      int j = i4 >> 7, k = i4 & 127;
      int rj = g * RESCAN_ROWS + j;
      if (rj < nflag) xs[j][k] = ((const float4*)(x + (size_t)flagged[rj] * DIM))[k];
    }
    __syncthreads();
    unsigned long long best[RESCAN_ROWS];
    #pragma unroll
    for (int j = 0; j < RESCAN_ROWS; ++j) best[j] = ~0ULL;
    #pragma unroll
    for (int cc = 0; cc < RESCAN_CHUNK / 256; ++cc) {
      const int c = c0 + cc * 256 + t;
      const float4* e4 = (const float4*)(emb + (size_t)c * DIM);
      float s0[RESCAN_ROWS], s1[RESCAN_ROWS], s2[RESCAN_ROWS], s3[RESCAN_ROWS];
      #pragma unroll
      for (int j = 0; j < RESCAN_ROWS; ++j) { s0[j] = s1[j] = s2[j] = s3[j] = 0.f; }
      for (int k = 0; k < DIM / 4; ++k) {
        float4 ev = e4[k];
        #pragma unroll
        for (int j = 0; j < RESCAN_ROWS; ++j) {
          float4 xv = xs[j][k];              // broadcast read, conflict-free
          s0[j] = fmaf(xv.x, ev.x, s0[j]);
          s1[j] = fmaf(xv.y, ev.y, s1[j]);
          s2[j] = fmaf(xv.z, ev.z, s2[j]);
          s3[j] = fmaf(xv.w, ev.w, s3[j]);
        }
      }
      const float en = enorm[c];
      #pragma unroll
      for (int j = 0; j < RESCAN_ROWS; ++j) {
        float d = en - 2.0f * ((s0[j] + s1[j]) + (s2[j] + s3[j]));
        unsigned long long p = pack_di(d, c);
        if (p < best[j]) best[j] = p;
      }
    }
    // wave reduce (packed u64 min == lexicographic (dist, idx) min)
    #pragma unroll
    for (int j = 0; j < RESCAN_ROWS; ++j) {
      #pragma unroll
      for (int off = 32; off > 0; off >>= 1) {
        unsigned long long o = __shfl_down(best[j], off);
        if (o < best[j]) best[j] = o;
      }
    }
    if (ln == 0) {
      #pragma unroll
      for (int j = 0; j < RESCAN_ROWS; ++j) wmin[wv][j] = best[j];
    }
    __syncthreads();
    if (t < RESCAN_ROWS) {
      int rj = g * RESCAN_ROWS + t;
      if (rj < nflag) {
        unsigned long long m = wmin[0][t];
        if (wmin[1][t] < m) m = wmin[1][t];
        if (wmin[2][t] < m) m = wmin[2][t];
        if (wmin[3][t] < m) m = wmin[3][t];
        atomicMin(&packed[flagged[rj]], m);
      }
    }
  }
}

// ---------------- kernel 5: gather + outputs + loss ----------------
__global__ __launch_bounds__(256) void vq_gather_kernel(
    const float* __restrict__ x, const float* __restrict__ emb,
    const int* __restrict__ idx, const int* __restrict__ flag,
    const unsigned long long* __restrict__ packed,
    float* __restrict__ out, float* __restrict__ quant,
    float* __restrict__ loss_slot) {
  __shared__ float wsum[4];
  const int wave = threadIdx.x >> 6;
  const int lane = threadIdx.x & 63;
  const int row  = blockIdx.x * 4 + wave;
  const int code = flag[row] ? (int)(packed[row] & 0xFFFFFFFFu) : idx[row];
  const float4* xp = (const float4*)(x   + (size_t)row  * DIM + lane * 8);
  const float4* ep = (const float4*)(emb + (size_t)code * DIM + lane * 8);
  float s = 0.0f;
  #pragma unroll
  for (int t = 0; t < 2; ++t) {
    float4 xv = xp[t];
    float4 ev = ep[t];
    float dx = ev.x - xv.x, dy = ev.y - xv.y, dz = ev.z - xv.z, dw = ev.w - xv.w;
    s += dx * dx + dy * dy + dz * dz + dw * dw;
    ((float4*)(out   + (size_t)row * DIM + lane * 8))[t] = ev;  // out == quantized (straight-through)
    ((float4*)(quant + (size_t)row * DIM + lane * 8))[t] = ev;
  }
  #pragma unroll
  for (int off = 32; off > 0; off >>= 1) s += __shfl_down(s, off);
  if (lane == 0) wsum[wave] = s;
  __syncthreads();
  if (threadIdx.x == 0) {
    float tot = wsum[0] + wsum[1] + wsum[2] + wsum[3];
    atomicAdd(loss_slot, tot * (1.25f / (float)OUT_ELEMS));
  }
}

extern "C" void kernel_launch(void* const* d_in, const int* in_sizes, int n_in,
                              void* d_out, int out_size, void* d_ws, size_t ws_size,
                              hipStream_t stream) {
  const float* x   = (const float*)d_in[0];   // [16384, 512]
  const float* emb = (const float*)d_in[1];   // [8192, 512]
  float* out   = (float*)d_out;
  float* quant = out + OUT_ELEMS;
  float* loss  = out + 2 * OUT_ELEMS;

  char* ws = (char*)d_ws;
  f16*   x16    = (f16*)(ws);                           // 16.78 MB
  f16*   e16    = (f16*)(ws + 16777216);                //  8.39 MB
  float* enorm  = (float*)(ws + 25165824);              // 32 KB
  float* cd1    = (float*)(ws + 25198592);              // 4 MB
  int*   ci1    = (int*)  (ws + 29392896);              // 4 MB
  float* cd2    = (float*)(ws + 33587200);              // 4 MB
  int*   idx    = (int*)  (ws + 37781504);              // 64 KB
  int*   flag   = (int*)  (ws + 37847040);              // 64 KB
  int*   counter= (int*)  (ws + 37912576);              // 4 B (+pad)
  int*   flagged= (int*)  (ws + 37912832);              // 64 KB
  unsigned long long* packed = (unsigned long long*)(ws + 37978368); // 128 KB

  vq_split_kernel<<<OUT_ELEMS / (8 * 256), 256, 0, stream>>>(x, x16);
  vq_split_enorm_kernel<<<K_CODES * 64 / 256, 256, 0, stream>>>(emb, e16, enorm, counter);
  vq_argmin_mfma_kernel<<<dim3(N_ROWS / TM, K_CODES / TN), 256, 0, stream>>>(
      x16, e16, enorm, cd1, ci1, cd2);
  vq_merge2_kernel<<<N_ROWS / 256, 256, 0, stream>>>(
      cd1, ci1, cd2, idx, flag, counter, flagged, packed, loss);
  vq_rescan_kernel<<<2048, 256, 0, stream>>>(x, emb, enorm, counter, flagged, packed);
  vq_gather_kernel<<<N_ROWS / 4, 256, 0, stream>>>(x, emb, idx, flag, packed, out, quant, loss);
}